// Round 5
// baseline (1616.339 us; speedup 1.0000x reference)
//
#include <hip/hip_runtime.h>

// ---------------------------------------------------------------------------
// VITS-style relative-attention encoder, MI355X round 13.
// vs round 12 (1.61 ms, REGRESSION): the 256-thread TN=128 conv with 6-uint4
// W prefetch spilled to scratch (WRITE_SIZE 16->117 MB, MfmaUtil 12.5%,
// first-dispatch 78us at 0.5% util = scratch init). This round keeps the
// TN=128 tile + register prefetch but moves conv_gemm to 512 threads/8 waves:
//  - per-wave acc[4][2] (32 VGPR, was 64); prefetch xr+hx+wr[3] (~20 VGPR).
//  - staging split across 2x threads: X row = tid>>2, W row = tid>>2 with
//    j-step == tap. No spills (~90 VGPR total).
// Everything else unchanged from round 12 (O-proj K-split partials, conv2
// KSPLIT=4, barrier-free fattn, [B,T,C] addln).
// ---------------------------------------------------------------------------

#define NLAYERS 6
#define BB 8
#define TT 512
#define CC 512
#define FF 2048
#define HH 8
#define DKK 64
#define WW 10

static_assert(CC == HH * DKK, "");

typedef __attribute__((ext_vector_type(8))) short short8;   // 8 bf16
typedef __attribute__((ext_vector_type(4))) float f32x4;
typedef unsigned short ushort;

#define BCTS ((size_t)BB * CC * TT)   // elements per [B,C,T] tensor

__device__ __forceinline__ ushort f2bs(float f) {   // fp32 -> bf16 RNE
    unsigned u = __float_as_uint(f);
    u = (u + 0x7FFFu + ((u >> 16) & 1u)) >> 16;
    return (ushort)u;
}
__device__ __forceinline__ float bf2f(ushort u) {
    return __uint_as_float(((unsigned)u) << 16);
}
__device__ __forceinline__ float wave_sum(float v) {
    #pragma unroll
    for (int off = 32; off > 0; off >>= 1) v += __shfl_xor(v, off, 64);
    return v;
}

// ---------------------------------------------------------------------------
// fp32 [B,C,T] -> fp32 [B,T,C] (masked) + bf16 [B,T,C] (masked), once at start
__global__ __launch_bounds__(256) void init_trans(const float* __restrict__ in,
                                                  const float* __restrict__ mask,
                                                  float* __restrict__ xf,
                                                  ushort* __restrict__ xt) {
    __shared__ float tile[32][33];
    const int t0 = blockIdx.x * 32;
    const int c0 = blockIdx.y * 32;
    const int b = blockIdx.z;
    const int col = threadIdx.x & 31;
    const int row = threadIdx.x >> 5;
    const float* src = in + ((size_t)b * CC + c0) * TT + t0;
    #pragma unroll
    for (int r = 0; r < 32; r += 8)
        tile[row + r][col] = src[(size_t)(row + r) * TT + col];  // tile[c][t]
    __syncthreads();
    #pragma unroll
    for (int r = 0; r < 32; r += 8) {
        const int t = t0 + row + r;
        const float mv = mask[b * TT + t];
        const float v = tile[col][row + r] * mv;
        const size_t idx = ((size_t)(b * TT) + t) * CC + c0 + col;
        xf[idx] = v;
        xt[idx] = f2bs(v);
    }
}

// fp32 [B,T,C] -> fp32 [B,C,T] masked (final output)
__global__ __launch_bounds__(256) void final_kernel(const float* __restrict__ xf,
                                                    const float* __restrict__ mask,
                                                    float* __restrict__ out) {
    __shared__ float tile[32][33];
    const int t0 = blockIdx.x * 32;
    const int c0 = blockIdx.y * 32;
    const int b = blockIdx.z;
    const int col = threadIdx.x & 31;
    const int row = threadIdx.x >> 5;
    #pragma unroll
    for (int r = 0; r < 32; r += 8)
        tile[row + r][col] = xf[((size_t)(b * TT) + t0 + row + r) * CC + c0 + col]; // tile[t][c]
    __syncthreads();
    #pragma unroll
    for (int r = 0; r < 32; r += 8) {
        const int c = c0 + row + r;
        const int t = t0 + col;
        out[((size_t)b * CC + c) * TT + t] = tile[col][row + r] * mask[b * TT + t];
    }
}

// ---------------------------------------------------------------------------
// Per-layer weight conversion, ONE launch (layouts as round 7/8).
__global__ __launch_bounds__(256) void wcvt_layer(const float* __restrict__ Wq,
                                                  const float* __restrict__ Wk,
                                                  const float* __restrict__ Wv,
                                                  const float* __restrict__ bq,
                                                  const float* __restrict__ bk,
                                                  const float* __restrict__ bv,
                                                  const float* __restrict__ Wo,
                                                  const float* __restrict__ W1,
                                                  const float* __restrict__ W2,
                                                  ushort* __restrict__ Wqkv,
                                                  float* __restrict__ bqkv,
                                                  ushort* __restrict__ Wot,
                                                  ushort* __restrict__ W1t,
                                                  ushort* __restrict__ W2t) {
    size_t i = (size_t)blockIdx.x * 256 + threadIdx.x;
    if (i < 1536)
        bqkv[i] = (i < 512) ? bq[i] : (i < 1024) ? bk[i - 512] : bv[i - 1024];
    if (i < 786432) {
        const int o = (int)(i >> 9), c = (int)(i & 511);
        const float* src = (o < 512) ? Wq : (o < 1024) ? Wk : Wv;
        Wqkv[i] = f2bs(src[(size_t)(o & 511) * 512 + c]);
        return;
    }
    i -= 786432;
    if (i < 262144) { Wot[i] = f2bs(Wo[i]); return; }
    i -= 262144;
    if (i < 3145728) {
        const int c = (int)(i & 511);
        const int o = (int)((i >> 9) & 2047);
        const int tap = (int)(i >> 20);
        W1t[i] = f2bs(W1[((size_t)o * 512 + c) * 3 + tap]);
        return;
    }
    i -= 3145728;
    if (i < 3145728) {
        const int c = (int)(i & 2047);
        const int o = (int)((i >> 11) & 511);
        const int tap = (int)(i >> 20);
        W2t[i] = f2bs(W2[((size_t)o * 2048 + c) * 3 + tap]);
    }
}

// ---------------------------------------------------------------------------
// Generic 128xTN GEMM -- used for QKV and O-proj.
// MODE 0: Out fp32 [B,T,O] partial (no bias) at kz*BCTS; grid.z = ksp
// MODE 2: QKV (O=1536): q,k -> bf16 [B,T,512]; v -> bf16 [B,512,T]
template <int MODE, int TN>
__global__ __launch_bounds__(256) void gemm128(const ushort* __restrict__ Wt,
                                               const float* __restrict__ bias,
                                               const ushort* __restrict__ Xin,
                                               void* __restrict__ Out,
                                               const float* __restrict__ mask,
                                               int O, int K, int taps, int kcs,
                                               int ksp) {
    const int blk = blockIdx.x;
    const int b = blk >> 2;
    const int t0 = (blk & 3) * 128;
    const int o0 = blockIdx.y * TN;
    const int kz = (MODE == 0) ? blockIdx.z : 0;
    const int tid = threadIdx.x;
    const int wid = tid >> 6, lane = tid & 63, ln = lane & 15, q = lane >> 4;
    constexpr int MF = (TN == 128) ? 4 : 2;
    const int msub = (TN == 128) ? (wid & 1) * 64 : wid * 32;
    const int nsub = (TN == 128) ? (wid >> 1) * 64 : 0;

    __shared__ ushort Xs[128][40];
    __shared__ ushort Ws[TN][40];

    f32x4 acc[MF][4] = {};

    const int Kc = (MODE == 0) ? (K / ksp) : K;
    const int cbase = kz * Kc;
    const int KC = Kc >> 5;
    const int NI = taps * KC;
    const int kcm = KC - 1;

    const int rx = tid >> 1;
    const int cx = (tid & 1) << 4;
    const int rw = (TN == 128) ? (tid >> 1) : (tid >> 2);
    const int cw = (TN == 128) ? ((tid & 1) << 4) : ((tid & 3) << 3);

    uint4 xr0, xr1, wr0, wr1;
    const uint4 zero = make_uint4(0u, 0u, 0u, 0u);

    auto load = [&](int it) {
        const int tap = it >> kcs;
        const int c0 = cbase + ((it & kcm) << 5);
        const int shift = (taps > 1) ? (tap - 1) : 0;
        const int tt = t0 + rx + shift;
        const bool okt = (tt >= 0) && (tt < TT);
        const ushort* xp = Xin + ((size_t)(b * TT + (okt ? tt : 0)) * K + c0 + cx);
        xr0 = okt ? *(const uint4*)xp : zero;
        xr1 = okt ? *(const uint4*)(xp + 8) : zero;
        const ushort* wp = Wt + ((size_t)(tap * O + o0 + rw) * K + c0 + cw);
        wr0 = *(const uint4*)wp;
        if (TN == 128) wr1 = *(const uint4*)(wp + 8);
    };

    load(0);
    for (int it = 0; it < NI; ++it) {
        __syncthreads();
        *(uint4*)&Xs[rx][cx] = xr0;
        *(uint4*)&Xs[rx][cx + 8] = xr1;
        *(uint4*)&Ws[rw][cw] = wr0;
        if (TN == 128) *(uint4*)&Ws[rw][cw + 8] = wr1;
        if (it + 1 < NI) load(it + 1);
        __syncthreads();
        short8 afr[MF], bfr[4];
        #pragma unroll
        for (int mi = 0; mi < MF; ++mi)
            afr[mi] = *(const short8*)&Xs[msub + mi * 16 + ln][q * 8];
        #pragma unroll
        for (int ni = 0; ni < 4; ++ni)
            bfr[ni] = *(const short8*)&Ws[nsub + ni * 16 + ln][q * 8];
        #pragma unroll
        for (int mi = 0; mi < MF; ++mi)
            #pragma unroll
            for (int ni = 0; ni < 4; ++ni)
                acc[mi][ni] = __builtin_amdgcn_mfma_f32_16x16x32_bf16(
                    afr[mi], bfr[ni], acc[mi][ni], 0, 0, 0);
    }

    #pragma unroll
    for (int ni = 0; ni < 4; ++ni) {
        const int o = o0 + nsub + ni * 16 + ln;
        #pragma unroll
        for (int mi = 0; mi < MF; ++mi) {
            const int t = t0 + msub + mi * 16 + q * 4;
            if (MODE == 0) {
                float* Op = (float*)Out + (size_t)kz * BCTS;
                #pragma unroll
                for (int r = 0; r < 4; ++r)
                    Op[((size_t)(b * TT) + t + r) * O + o] = acc[mi][ni][r];
            } else {
                const float bv = bias[o];
                ushort* Op = (ushort*)Out;
                const int which = o >> 9, oo = o & 511;
                if (which < 2) {
                    #pragma unroll
                    for (int r = 0; r < 4; ++r)
                        Op[(size_t)which * BCTS + ((size_t)(b * TT) + t + r) * CC + oo] =
                            f2bs(acc[mi][ni][r] + bv);
                } else {
                    ushort tmp[4];
                    #pragma unroll
                    for (int r = 0; r < 4; ++r) tmp[r] = f2bs(acc[mi][ni][r] + bv);
                    *(uint2*)&Op[2 * BCTS + ((size_t)(b * CC) + oo) * TT + t] =
                        *(const uint2*)tmp;
                }
            }
        }
    }
}

// ---------------------------------------------------------------------------
// Conv GEMM, 512 threads / 8 waves, 128x128 tile, halo-staged X, register
// prefetch with low pressure (xr + hx + wr[3] ~ 20 VGPR; acc[4][2] = 32).
//  D[t][o] = sum_{tap,c in kz-range} Xin[b][t+tap-1][c] * Wt[tap][o][c]
// MODE 1: Out bf16 [B,T,O] = relu(D + bias) * mask[t]             (conv1)
// MODE 3: fp32 [B,T,O] partial = D; kz<2 -> Out, kz>=2 -> Out2    (conv2)
template <int KSPLIT, int MODE>
__global__ __launch_bounds__(512) void conv_gemm(const ushort* __restrict__ Wt,
                                                 const float* __restrict__ bias,
                                                 const ushort* __restrict__ Xin,
                                                 void* __restrict__ Out,
                                                 float* __restrict__ Out2,
                                                 const float* __restrict__ mask,
                                                 int O, int K) {
    const int blk = blockIdx.x;
    const int b = blk >> 2;
    const int t0 = (blk & 3) * 128;
    const int o0 = blockIdx.y * 128;
    const int kz = (KSPLIT > 1) ? blockIdx.z : 0;
    const int tid = threadIdx.x;
    const int wid = tid >> 6, lane = tid & 63, ln = lane & 15, q = lane >> 4;
    const int msub = (wid & 1) * 64;    // 64 t-rows per wave
    const int nsub = (wid >> 1) * 32;   // 32 o-cols per wave

    __shared__ ushort Xs[130][40];      // rows t0-1 .. t0+128
    __shared__ ushort Ws[384][40];      // [tap*128 + o][c]

    f32x4 acc[4][2] = {};

    const int Kc = K / KSPLIT;
    const int cbase = kz * Kc;
    const int NC = Kc >> 5;

    const int rx = tid >> 2;            // 0..127: X row AND W row-within-tap
    const int cx = (tid & 3) << 3;      // 8-ch (16B) column slot

    const ushort* Xb = Xin + (size_t)b * TT * K;

    uint4 xr, hx, wr[3];
    auto load = [&](int cc) {
        const int c0 = cbase + (cc << 5);
        xr = *(const uint4*)(Xb + (size_t)(t0 + rx) * K + c0 + cx);
        if (tid < 8) {
            const int tg = t0 + ((tid < 4) ? -1 : 128);
            hx = make_uint4(0u, 0u, 0u, 0u);
            if (tg >= 0 && tg < TT)
                hx = *(const uint4*)(Xb + (size_t)tg * K + c0 + ((tid & 3) << 3));
        }
        #pragma unroll
        for (int j = 0; j < 3; ++j)   // j == tap
            wr[j] = *(const uint4*)(Wt + ((size_t)(j * O + o0 + rx)) * K + c0 + cx);
    };

    load(0);
    for (int cc = 0; cc < NC; ++cc) {
        __syncthreads();
        *(uint4*)&Xs[rx + 1][cx] = xr;
        if (tid < 8) *(uint4*)&Xs[(tid < 4) ? 0 : 129][(tid & 3) << 3] = hx;
        #pragma unroll
        for (int j = 0; j < 3; ++j)
            *(uint4*)&Ws[j * 128 + rx][cx] = wr[j];
        if (cc + 1 < NC) load(cc + 1);
        __syncthreads();
        #pragma unroll
        for (int tap = 0; tap < 3; ++tap) {
            short8 afr[4], bfr[2];
            #pragma unroll
            for (int mi = 0; mi < 4; ++mi)
                afr[mi] = *(const short8*)&Xs[msub + mi * 16 + ln + tap][q * 8];
            #pragma unroll
            for (int ni = 0; ni < 2; ++ni)
                bfr[ni] = *(const short8*)&Ws[tap * 128 + nsub + ni * 16 + ln][q * 8];
            #pragma unroll
            for (int mi = 0; mi < 4; ++mi)
                #pragma unroll
                for (int ni = 0; ni < 2; ++ni)
                    acc[mi][ni] = __builtin_amdgcn_mfma_f32_16x16x32_bf16(
                        afr[mi], bfr[ni], acc[mi][ni], 0, 0, 0);
        }
    }

    #pragma unroll
    for (int ni = 0; ni < 2; ++ni) {
        const int o = o0 + nsub + ni * 16 + ln;
        #pragma unroll
        for (int mi = 0; mi < 4; ++mi) {
            const int t = t0 + msub + mi * 16 + q * 4;
            if (MODE == 1) {
                const float bv = bias[o];
                ushort* Op = (ushort*)Out;
                #pragma unroll
                for (int r = 0; r < 4; ++r) {
                    float v = fmaxf(acc[mi][ni][r] + bv, 0.f) * mask[b * TT + t + r];
                    Op[((size_t)(b * TT) + t + r) * (size_t)O + o] = f2bs(v);
                }
            } else {
                float* Op = (kz < 2) ? ((float*)Out + (size_t)kz * BCTS)
                                     : (Out2 + (size_t)(kz - 2) * BCTS);
                #pragma unroll
                for (int r = 0; r < 4; ++r)
                    Op[((size_t)(b * TT) + t + r) * O + o] = acc[mi][ni][r];
            }
        }
    }
}

// ---------------------------------------------------------------------------
// Fused relative-position attention: one independent wave per 16 q-rows.
// (unchanged from round 11)
__global__ __launch_bounds__(256) void fattn_kernel(const ushort* __restrict__ qkvt,
                                                    const float* __restrict__ mask,
                                                    const float* __restrict__ erk,
                                                    const float* __restrict__ erv,
                                                    ushort* __restrict__ xto) {
    const int tid = threadIdx.x;
    const int wm = tid >> 6;
    const int lane = tid & 63;
    const int ln = lane & 15;
    const int q4 = lane >> 4;
    const int bh = blockIdx.y;
    const int b = bh >> 3, h = bh & 7;
    const int t0g = blockIdx.x * 64 + wm * 16;

    __shared__ float ervs[2 * WW + 1][DKK];
    __shared__ float msS[TT];
    __shared__ float relS[4][16][22];
    __shared__ float band[4][16][24];
    __shared__ ushort Pt[4][16][40];

    for (int i = tid; i < (2 * WW + 1) * DKK; i += 256)
        ervs[i / DKK][i % DKK] = erv[i];
    for (int i = tid; i < TT; i += 256)
        msS[i] = mask[b * TT + i];

    #pragma unroll
    for (int i = 0; i < 6; ++i) {
        const int idx = lane + i * 64;
        ((float*)band[wm])[idx] = -1e30f;
    }

    const ushort* qrow = qkvt + ((size_t)(b * TT + t0g + ln) * CC + h * DKK);
    const short8 qb0 = *(const short8*)(qrow + q4 * 8);
    const short8 qb1 = *(const short8*)(qrow + 32 + q4 * 8);

    {
        const float* ekL = erk;
        short8 ea0, ea1;
        {
            const float* ep = ekL + ln * DKK + q4 * 8;
            #pragma unroll
            for (int j = 0; j < 8; ++j) ea0[j] = (short)f2bs(ep[j]);
            #pragma unroll
            for (int j = 0; j < 8; ++j) ea1[j] = (short)f2bs(ep[32 + j]);
        }
        f32x4 c0 = {};
        c0 = __builtin_amdgcn_mfma_f32_16x16x32_bf16(ea0, qb0, c0, 0, 0, 0);
        c0 = __builtin_amdgcn_mfma_f32_16x16x32_bf16(ea1, qb1, c0, 0, 0, 0);
        #pragma unroll
        for (int r = 0; r < 4; ++r)
            relS[wm][ln][q4 * 4 + r] = c0[r] * 0.125f;
        short8 eb0 = {}, eb1 = {};
        if (ln < 2 * WW + 1 - 16) {
            const float* ep = ekL + (16 + ln) * DKK + q4 * 8;
            #pragma unroll
            for (int j = 0; j < 8; ++j) eb0[j] = (short)f2bs(ep[j]);
            #pragma unroll
            for (int j = 0; j < 8; ++j) eb1[j] = (short)f2bs(ep[32 + j]);
        }
        f32x4 c1 = {};
        c1 = __builtin_amdgcn_mfma_f32_16x16x32_bf16(eb0, qb0, c1, 0, 0, 0);
        c1 = __builtin_amdgcn_mfma_f32_16x16x32_bf16(eb1, qb1, c1, 0, 0, 0);
        #pragma unroll
        for (int r = 0; r < 4; ++r) {
            const int w = 16 + q4 * 4 + r;
            if (w < 2 * WW + 1) relS[wm][ln][w] = c1[r] * 0.125f;
        }
    }

    __syncthreads();

    const float mt = msS[t0g + ln];

    float m_run = -1e30f, l_run = 0.f;
    f32x4 Oacc[4] = {};

    const ushort* Kbase = qkvt + BCTS + ((size_t)(b * TT) * CC + h * DKK);
    const ushort* Vbase = qkvt + 2 * BCTS + ((size_t)(b * CC + h * DKK) * TT);

    for (int s0 = 0; s0 < TT; s0 += 32) {
        const ushort* klo = Kbase + (size_t)(s0 + ln) * CC;
        const ushort* khi = klo + 16 * CC;
        const short8 ka0 = *(const short8*)(klo + q4 * 8);
        const short8 ka1 = *(const short8*)(klo + 32 + q4 * 8);
        const short8 kb0 = *(const short8*)(khi + q4 * 8);
        const short8 kb1 = *(const short8*)(khi + 32 + q4 * 8);

        f32x4 slo = {}, shi = {};
        slo = __builtin_amdgcn_mfma_f32_16x16x32_bf16(ka0, qb0, slo, 0, 0, 0);
        slo = __builtin_amdgcn_mfma_f32_16x16x32_bf16(ka1, qb1, slo, 0, 0, 0);
        shi = __builtin_amdgcn_mfma_f32_16x16x32_bf16(kb0, qb0, shi, 0, 0, 0);
        shi = __builtin_amdgcn_mfma_f32_16x16x32_bf16(kb1, qb1, shi, 0, 0, 0);

        float v[2][4];
        float bmax = -1e30f;
        const int tg = t0g + ln;
        #pragma unroll
        for (int half = 0; half < 2; ++half) {
            #pragma unroll
            for (int r = 0; r < 4; ++r) {
                const int s = s0 + half * 16 + q4 * 4 + r;
                const int wb = s - tg + WW;
                float vv = (half ? shi[r] : slo[r]) * 0.125f;
                if ((unsigned)wb <= 2u * WW) vv += relS[wm][ln][wb];
                if (mt * msS[s] == 0.f) vv = -1e4f;
                if ((unsigned)wb <= 2u * WW) band[wm][ln][wb] = vv;
                v[half][r] = vv;
                bmax = fmaxf(bmax, vv);
            }
        }
        bmax = fmaxf(bmax, __shfl_xor(bmax, 16, 64));
        bmax = fmaxf(bmax, __shfl_xor(bmax, 32, 64));

        const float mnew = fmaxf(m_run, bmax);
        const float alpha = __expf(m_run - mnew);
        m_run = mnew;

        float rsum = 0.f;
        ushort pb[8];
        #pragma unroll
        for (int half = 0; half < 2; ++half)
            #pragma unroll
            for (int r = 0; r < 4; ++r) {
                const float p = __expf(v[half][r] - mnew);
                rsum += p;
                pb[half * 4 + r] = f2bs(p);
            }
        rsum += __shfl_xor(rsum, 16, 64);
        rsum += __shfl_xor(rsum, 32, 64);
        l_run = l_run * alpha + rsum;

        *(uint2*)&Pt[wm][ln][q4 * 4] = *(const uint2*)&pb[0];
        *(uint2*)&Pt[wm][ln][16 + q4 * 4] = *(const uint2*)&pb[4];

        #pragma unroll
        for (int r = 0; r < 4; ++r) {
            const float alr = __shfl(alpha, q4 * 4 + r, 64);
            #pragma unroll
            for (int dt = 0; dt < 4; ++dt) Oacc[dt][r] *= alr;
        }

        const short8 pa = *(const short8*)&Pt[wm][ln][q4 * 8];
        #pragma unroll
        for (int dt = 0; dt < 4; ++dt) {
            const short8 vb = *(const short8*)(Vbase + (size_t)(dt * 16 + ln) * TT + s0 + q4 * 8);
            Oacc[dt] = __builtin_amdgcn_mfma_f32_16x16x32_bf16(pa, vb, Oacc[dt], 0, 0, 0);
        }
    }

    float mr[4], invl[4];
    #pragma unroll
    for (int r = 0; r < 4; ++r) {
        mr[r] = __shfl(m_run, q4 * 4 + r, 64);
        invl[r] = 1.f / __shfl(l_run, q4 * 4 + r, 64);
    }
    f32x4 racc[4] = {};
    for (int w = 0; w <= 2 * WW; ++w) {
        float ev[4];
        #pragma unroll
        for (int dt = 0; dt < 4; ++dt) ev[dt] = ervs[w][dt * 16 + ln];
        #pragma unroll
        for (int r = 0; r < 4; ++r) {
            const float pw = __expf(band[wm][q4 * 4 + r][w] - mr[r]);
            #pragma unroll
            for (int dt = 0; dt < 4; ++dt) racc[dt][r] += pw * ev[dt];
        }
    }
    #pragma unroll
    for (int r = 0; r < 4; ++r) {
        const int t = t0g + q4 * 4 + r;
        #pragma unroll
        for (int dt = 0; dt < 4; ++dt)
            xto[((size_t)(b * TT) + t) * CC + h * DKK + dt * 16 + ln] =
                f2bs((Oacc[dt][r] + racc[dt][r]) * invl[r]);
    }
}

// ---------------------------------------------------------------------------
// x = LN(x + y*(maskY?m:1)), y = sum(p0..p3 present) (+ biasc[c]);
// emits Xt bf16 [B,T,C]. All tensors [B,T,C]. One wave per (b,t) row.
__global__ __launch_bounds__(256) void addln_kernel(float* __restrict__ x,
                                                    const float* __restrict__ p0,
                                                    const float* __restrict__ p1,
                                                    const float* __restrict__ p2,
                                                    const float* __restrict__ p3,
                                                    const float* __restrict__ biasc,
                                                    const float* __restrict__ g,
                                                    const float* __restrict__ bt,
                                                    const float* __restrict__ mask,
                                                    int maskY,
                                                    ushort* __restrict__ xtout,
                                                    int maskOut) {
    const int row = blockIdx.x * 4 + (threadIdx.x >> 6);   // b*TT + t
    const int lane = threadIdx.x & 63;
    const float m = mask[row];
    const float mv = maskY ? m : 1.f;
    const float mo = maskOut ? m : 1.f;
    const size_t base = (size_t)row * CC;
    const int c0 = lane * 8;

    f32x4 y0 = *(const f32x4*)(p0 + base + c0);
    f32x4 y1 = *(const f32x4*)(p0 + base + c0 + 4);
    if (p1) {
        y0 += *(const f32x4*)(p1 + base + c0);
        y1 += *(const f32x4*)(p1 + base + c0 + 4);
    }
    if (p2) {
        y0 += *(const f32x4*)(p2 + base + c0);
        y1 += *(const f32x4*)(p2 + base + c0 + 4);
    }
    if (p3) {
        y0 += *(const f32x4*)(p3 + base + c0);
        y1 += *(const f32x4*)(p3 + base + c0 + 4);
    }
    if (biasc) {
        y0 += *(const f32x4*)(biasc + c0);
        y1 += *(const f32x4*)(biasc + c0 + 4);
    }

    f32x4 a0 = *(const f32x4*)(x + base + c0);
    f32x4 a1 = *(const f32x4*)(x + base + c0 + 4);
    f32x4 v0, v1;
    #pragma unroll
    for (int r = 0; r < 4; ++r) {
        v0[r] = a0[r] + y0[r] * mv;
        v1[r] = a1[r] + y1[r] * mv;
    }

    float s = 0.f, s2 = 0.f;
    #pragma unroll
    for (int r = 0; r < 4; ++r) {
        s += v0[r] + v1[r];
        s2 += v0[r] * v0[r] + v1[r] * v1[r];
    }
    s = wave_sum(s);
    s2 = wave_sum(s2);
    const float mean = s * (1.f / CC);
    const float var = s2 * (1.f / CC) - mean * mean;
    const float rstd = rsqrtf(var + 1e-5f);

    f32x4 g0 = *(const f32x4*)(g + c0);
    f32x4 g1v = *(const f32x4*)(g + c0 + 4);
    f32x4 bt0 = *(const f32x4*)(bt + c0);
    f32x4 bt1 = *(const f32x4*)(bt + c0 + 4);
    f32x4 o0, o1;
    ushort ob[8];
    #pragma unroll
    for (int r = 0; r < 4; ++r) {
        o0[r] = (v0[r] - mean) * rstd * g0[r] + bt0[r];
        o1[r] = (v1[r] - mean) * rstd * g1v[r] + bt1[r];
        ob[r] = f2bs(o0[r] * mo);
        ob[4 + r] = f2bs(o1[r] * mo);
    }
    *(f32x4*)(x + base + c0) = o0;
    *(f32x4*)(x + base + c0 + 4) = o1;
    *(uint4*)(xtout + base + c0) = *(const uint4*)ob;
}

// ---------------------------------------------------------------------------
extern "C" void kernel_launch(void* const* d_in, const int* in_sizes, int n_in,
                              void* d_out, int out_size, void* d_ws, size_t ws_size,
                              hipStream_t stream) {
    const float* x_in = (const float*)d_in[0];
    const float* mask = (const float*)d_in[1];
    const float* Wq = (const float*)d_in[2];
    const float* bq = (const float*)d_in[3];
    const float* Wk = (const float*)d_in[4];
    const float* bk = (const float*)d_in[5];
    const float* Wv = (const float*)d_in[6];
    const float* bv = (const float*)d_in[7];
    const float* Wo = (const float*)d_in[8];
    const float* bo = (const float*)d_in[9];
    const float* erk = (const float*)d_in[10];
    const float* erv = (const float*)d_in[11];
    const float* g1 = (const float*)d_in[12];
    const float* b1 = (const float*)d_in[13];
    const float* g2 = (const float*)d_in[14];
    const float* b2 = (const float*)d_in[15];
    const float* W1 = (const float*)d_in[16];
    const float* bf1 = (const float*)d_in[17];
    const float* W2 = (const float*)d_in[18];
    const float* bf2 = (const float*)d_in[19];

    float* xf = (float*)d_ws;                    // fp32 [B,T,C]
    ushort* Xt = (ushort*)(xf + BCTS);           // bf16 [B,T,C]
    ushort* qkvt = Xt + BCTS;
    ushort* Xto = qkvt + 3 * BCTS;
    float* parts = (float*)(Xto + BCTS);         // fp32 [B,T,C] p0 | p1
    ushort* Midt = (ushort*)(parts + 2 * BCTS);  // [B,T,F] bf16
    ushort* Wqkv = Midt + 4 * BCTS;
    float* bqkv = (float*)(Wqkv + (size_t)1536 * 512);
    ushort* Wot = (ushort*)(bqkv + 1536);
    ushort* W1t = Wot + (size_t)CC * CC;
    ushort* W2t = W1t + (size_t)3 * FF * CC;

    // conv2 partials p2,p3 reuse the qkvt region (dead during the FFN phase;
    // p3 also covers Xto, which is dead after the O-projection reads it).
    float* P23 = (float*)qkvt;

    init_trans<<<dim3(TT / 32, CC / 32, BB), 256, 0, stream>>>(x_in, mask, xf, Xt);

    const size_t nW = 786432 + 262144 + 3145728 + 3145728;
    const int wcvtBlocks = (int)((nW + 255) / 256);

    for (int L = 0; L < NLAYERS; ++L) {
        wcvt_layer<<<wcvtBlocks, 256, 0, stream>>>(
            Wq + (size_t)L * CC * CC, Wk + (size_t)L * CC * CC, Wv + (size_t)L * CC * CC,
            bq + (size_t)L * CC, bk + (size_t)L * CC, bv + (size_t)L * CC,
            Wo + (size_t)L * CC * CC,
            W1 + (size_t)L * 3 * FF * CC, W2 + (size_t)L * 3 * FF * CC,
            Wqkv, bqkv, Wot, W1t, W2t);

        // fused QKV (N=1536)
        gemm128<2, 128><<<dim3(32, 12), 256, 0, stream>>>(
            Wqkv, bqkv, Xt, qkvt, mask, 1536, CC, 1, 4, 1);

        // fused attention (barrier-free waves, writes Xto directly)
        fattn_kernel<<<dim3(TT / 64, BB * HH), 256, 0, stream>>>(
            qkvt, mask, erk + (size_t)L * (2 * WW + 1) * DKK,
            erv + (size_t)L * (2 * WW + 1) * DKK, Xto);

        // O-projection (K-split x2, raw partials) + residual LN (bias in LN)
        gemm128<0, 64><<<dim3(32, 8, 2), 256, 0, stream>>>(
            Wot, nullptr, Xto, parts, mask, CC, CC, 1, 4, 2);
        addln_kernel<<<BB * TT / 4, 256, 0, stream>>>(
            xf, parts, parts + BCTS, nullptr, nullptr, bo + (size_t)L * CC,
            g1 + (size_t)L * CC, b1 + (size_t)L * CC, mask, 0, Xt, 1);

        // FFN: conv1 -> conv2 (K-split x4) -> LN  (512-thread conv blocks)
        conv_gemm<1, 1><<<dim3(32, FF / 128, 1), 512, 0, stream>>>(
            W1t, bf1 + (size_t)L * FF, Xt, Midt, nullptr, mask, FF, CC);
        conv_gemm<4, 3><<<dim3(32, CC / 128, 4), 512, 0, stream>>>(
            W2t, nullptr, Midt, parts, P23, mask, CC, FF);
        addln_kernel<<<BB * TT / 4, 256, 0, stream>>>(
            xf, parts, parts + BCTS, P23, P23 + BCTS, bf2 + (size_t)L * CC,
            g2 + (size_t)L * CC, b2 + (size_t)L * CC, mask, 1, Xt, 0);
    }

    final_kernel<<<dim3(TT / 32, CC / 32, BB), 256, 0, stream>>>(xf, mask, (float*)d_out);
}

// Round 6
// 1225.098 us; speedup vs baseline: 1.3194x; 1.3194x over previous
//
#include <hip/hip_runtime.h>

// ---------------------------------------------------------------------------
// VITS-style relative-attention encoder, MI355X round 14.
// vs rounds 12/13 (1.61 ms, REGRESSIONS): both prefetch variants spilled to
// scratch (WRITE_SIZE 114 MB, round 13 VGPR=48 -> compiler chased 8 waves/EU
// and spilled the held prefetch regs). Revert conv to the proven round-3
// structure (direct global->LDS staging, no held regs, VGPR 44) and attack
// its measured limits instead:
//  - conv2 KSPLIT 2->4: 1024 blocks (4/CU grid) for cross-block latency
//    overlap; partials p2,p3 in the dead qkvt/Xto region.
//  - LDS XOR swizzle (col ^= ((row>>3)&1)<<3) on conv tiles: kills the
//    stride-80B 8-way bank conflict (lanes ln vs ln+8) -> 2-way (free).
// Keeps round 12/13 wins: O-proj K-split x2 raw partials + 4-input addln.
// ---------------------------------------------------------------------------

#define NLAYERS 6
#define BB 8
#define TT 512
#define CC 512
#define FF 2048
#define HH 8
#define DKK 64
#define WW 10

static_assert(CC == HH * DKK, "");

typedef __attribute__((ext_vector_type(8))) short short8;   // 8 bf16
typedef __attribute__((ext_vector_type(4))) float f32x4;
typedef unsigned short ushort;

#define BCTS ((size_t)BB * CC * TT)   // elements per [B,C,T] tensor

__device__ __forceinline__ ushort f2bs(float f) {   // fp32 -> bf16 RNE
    unsigned u = __float_as_uint(f);
    u = (u + 0x7FFFu + ((u >> 16) & 1u)) >> 16;
    return (ushort)u;
}
__device__ __forceinline__ float bf2f(ushort u) {
    return __uint_as_float(((unsigned)u) << 16);
}
__device__ __forceinline__ float wave_sum(float v) {
    #pragma unroll
    for (int off = 32; off > 0; off >>= 1) v += __shfl_xor(v, off, 64);
    return v;
}
// LDS column swizzle: toggle 16B slot on row bit 3 (fixes stride-80B aliasing)
__device__ __forceinline__ int swz(int row, int col) {
    return col ^ (((row >> 3) & 1) << 3);
}

// ---------------------------------------------------------------------------
// fp32 [B,C,T] -> fp32 [B,T,C] (masked) + bf16 [B,T,C] (masked), once at start
__global__ __launch_bounds__(256) void init_trans(const float* __restrict__ in,
                                                  const float* __restrict__ mask,
                                                  float* __restrict__ xf,
                                                  ushort* __restrict__ xt) {
    __shared__ float tile[32][33];
    const int t0 = blockIdx.x * 32;
    const int c0 = blockIdx.y * 32;
    const int b = blockIdx.z;
    const int col = threadIdx.x & 31;
    const int row = threadIdx.x >> 5;
    const float* src = in + ((size_t)b * CC + c0) * TT + t0;
    #pragma unroll
    for (int r = 0; r < 32; r += 8)
        tile[row + r][col] = src[(size_t)(row + r) * TT + col];  // tile[c][t]
    __syncthreads();
    #pragma unroll
    for (int r = 0; r < 32; r += 8) {
        const int t = t0 + row + r;
        const float mv = mask[b * TT + t];
        const float v = tile[col][row + r] * mv;
        const size_t idx = ((size_t)(b * TT) + t) * CC + c0 + col;
        xf[idx] = v;
        xt[idx] = f2bs(v);
    }
}

// fp32 [B,T,C] -> fp32 [B,C,T] masked (final output)
__global__ __launch_bounds__(256) void final_kernel(const float* __restrict__ xf,
                                                    const float* __restrict__ mask,
                                                    float* __restrict__ out) {
    __shared__ float tile[32][33];
    const int t0 = blockIdx.x * 32;
    const int c0 = blockIdx.y * 32;
    const int b = blockIdx.z;
    const int col = threadIdx.x & 31;
    const int row = threadIdx.x >> 5;
    #pragma unroll
    for (int r = 0; r < 32; r += 8)
        tile[row + r][col] = xf[((size_t)(b * TT) + t0 + row + r) * CC + c0 + col]; // tile[t][c]
    __syncthreads();
    #pragma unroll
    for (int r = 0; r < 32; r += 8) {
        const int c = c0 + row + r;
        const int t = t0 + col;
        out[((size_t)b * CC + c) * TT + t] = tile[col][row + r] * mask[b * TT + t];
    }
}

// ---------------------------------------------------------------------------
// Per-layer weight conversion, ONE launch (layouts as round 7/8).
__global__ __launch_bounds__(256) void wcvt_layer(const float* __restrict__ Wq,
                                                  const float* __restrict__ Wk,
                                                  const float* __restrict__ Wv,
                                                  const float* __restrict__ bq,
                                                  const float* __restrict__ bk,
                                                  const float* __restrict__ bv,
                                                  const float* __restrict__ Wo,
                                                  const float* __restrict__ W1,
                                                  const float* __restrict__ W2,
                                                  ushort* __restrict__ Wqkv,
                                                  float* __restrict__ bqkv,
                                                  ushort* __restrict__ Wot,
                                                  ushort* __restrict__ W1t,
                                                  ushort* __restrict__ W2t) {
    size_t i = (size_t)blockIdx.x * 256 + threadIdx.x;
    if (i < 1536)
        bqkv[i] = (i < 512) ? bq[i] : (i < 1024) ? bk[i - 512] : bv[i - 1024];
    if (i < 786432) {
        const int o = (int)(i >> 9), c = (int)(i & 511);
        const float* src = (o < 512) ? Wq : (o < 1024) ? Wk : Wv;
        Wqkv[i] = f2bs(src[(size_t)(o & 511) * 512 + c]);
        return;
    }
    i -= 786432;
    if (i < 262144) { Wot[i] = f2bs(Wo[i]); return; }
    i -= 262144;
    if (i < 3145728) {
        const int c = (int)(i & 511);
        const int o = (int)((i >> 9) & 2047);
        const int tap = (int)(i >> 20);
        W1t[i] = f2bs(W1[((size_t)o * 512 + c) * 3 + tap]);
        return;
    }
    i -= 3145728;
    if (i < 3145728) {
        const int c = (int)(i & 2047);
        const int o = (int)((i >> 11) & 511);
        const int tap = (int)(i >> 20);
        W2t[i] = f2bs(W2[((size_t)o * 2048 + c) * 3 + tap]);
    }
}

// ---------------------------------------------------------------------------
// Generic 128xTN GEMM -- used for QKV and O-proj.
// MODE 0: Out fp32 [B,T,O] partial (no bias) at kz*BCTS; grid.z = ksp
// MODE 2: QKV (O=1536): q,k -> bf16 [B,T,512]; v -> bf16 [B,512,T]
template <int MODE, int TN>
__global__ __launch_bounds__(256) void gemm128(const ushort* __restrict__ Wt,
                                               const float* __restrict__ bias,
                                               const ushort* __restrict__ Xin,
                                               void* __restrict__ Out,
                                               const float* __restrict__ mask,
                                               int O, int K, int taps, int kcs,
                                               int ksp) {
    const int blk = blockIdx.x;
    const int b = blk >> 2;
    const int t0 = (blk & 3) * 128;
    const int o0 = blockIdx.y * TN;
    const int kz = (MODE == 0) ? blockIdx.z : 0;
    const int tid = threadIdx.x;
    const int wid = tid >> 6, lane = tid & 63, ln = lane & 15, q = lane >> 4;
    constexpr int MF = (TN == 128) ? 4 : 2;
    const int msub = (TN == 128) ? (wid & 1) * 64 : wid * 32;
    const int nsub = (TN == 128) ? (wid >> 1) * 64 : 0;

    __shared__ ushort Xs[128][40];
    __shared__ ushort Ws[TN][40];

    f32x4 acc[MF][4] = {};

    const int Kc = (MODE == 0) ? (K / ksp) : K;
    const int cbase = kz * Kc;
    const int KC = Kc >> 5;
    const int NI = taps * KC;
    const int kcm = KC - 1;

    const int rx = tid >> 1;
    const int cx = (tid & 1) << 4;
    const int rw = (TN == 128) ? (tid >> 1) : (tid >> 2);
    const int cw = (TN == 128) ? ((tid & 1) << 4) : ((tid & 3) << 3);

    uint4 xr0, xr1, wr0, wr1;
    const uint4 zero = make_uint4(0u, 0u, 0u, 0u);

    auto load = [&](int it) {
        const int tap = it >> kcs;
        const int c0 = cbase + ((it & kcm) << 5);
        const int shift = (taps > 1) ? (tap - 1) : 0;
        const int tt = t0 + rx + shift;
        const bool okt = (tt >= 0) && (tt < TT);
        const ushort* xp = Xin + ((size_t)(b * TT + (okt ? tt : 0)) * K + c0 + cx);
        xr0 = okt ? *(const uint4*)xp : zero;
        xr1 = okt ? *(const uint4*)(xp + 8) : zero;
        const ushort* wp = Wt + ((size_t)(tap * O + o0 + rw) * K + c0 + cw);
        wr0 = *(const uint4*)wp;
        if (TN == 128) wr1 = *(const uint4*)(wp + 8);
    };

    load(0);
    for (int it = 0; it < NI; ++it) {
        __syncthreads();
        *(uint4*)&Xs[rx][cx] = xr0;
        *(uint4*)&Xs[rx][cx + 8] = xr1;
        *(uint4*)&Ws[rw][cw] = wr0;
        if (TN == 128) *(uint4*)&Ws[rw][cw + 8] = wr1;
        if (it + 1 < NI) load(it + 1);
        __syncthreads();
        short8 afr[MF], bfr[4];
        #pragma unroll
        for (int mi = 0; mi < MF; ++mi)
            afr[mi] = *(const short8*)&Xs[msub + mi * 16 + ln][q * 8];
        #pragma unroll
        for (int ni = 0; ni < 4; ++ni)
            bfr[ni] = *(const short8*)&Ws[nsub + ni * 16 + ln][q * 8];
        #pragma unroll
        for (int mi = 0; mi < MF; ++mi)
            #pragma unroll
            for (int ni = 0; ni < 4; ++ni)
                acc[mi][ni] = __builtin_amdgcn_mfma_f32_16x16x32_bf16(
                    afr[mi], bfr[ni], acc[mi][ni], 0, 0, 0);
    }

    #pragma unroll
    for (int ni = 0; ni < 4; ++ni) {
        const int o = o0 + nsub + ni * 16 + ln;
        #pragma unroll
        for (int mi = 0; mi < MF; ++mi) {
            const int t = t0 + msub + mi * 16 + q * 4;
            if (MODE == 0) {
                float* Op = (float*)Out + (size_t)kz * BCTS;
                #pragma unroll
                for (int r = 0; r < 4; ++r)
                    Op[((size_t)(b * TT) + t + r) * O + o] = acc[mi][ni][r];
            } else {
                const float bv = bias[o];
                ushort* Op = (ushort*)Out;
                const int which = o >> 9, oo = o & 511;
                if (which < 2) {
                    #pragma unroll
                    for (int r = 0; r < 4; ++r)
                        Op[(size_t)which * BCTS + ((size_t)(b * TT) + t + r) * CC + oo] =
                            f2bs(acc[mi][ni][r] + bv);
                } else {
                    ushort tmp[4];
                    #pragma unroll
                    for (int r = 0; r < 4; ++r) tmp[r] = f2bs(acc[mi][ni][r] + bv);
                    *(uint2*)&Op[2 * BCTS + ((size_t)(b * CC) + oo) * TT + t] =
                        *(const uint2*)tmp;
                }
            }
        }
    }
}

// ---------------------------------------------------------------------------
// Conv GEMM (round-3 structure: direct staging, no held prefetch regs) with
// halo-staged X + LDS col swizzle. All 3 taps computed from one LDS tile.
//  D[t][o] = sum_{tap,c in kz-range} Xin[b][t+tap-1][c] * Wt[tap][o][c]
// MODE 1: Out bf16 [B,T,O] = relu(D + bias) * mask[t]             (conv1)
// MODE 3: fp32 [B,T,O] partial = D; kz<2 -> Out, kz>=2 -> Out2    (conv2)
template <int TN, int KSPLIT, int MODE>
__global__ __launch_bounds__(256) void conv_gemm(const ushort* __restrict__ Wt,
                                                 const float* __restrict__ bias,
                                                 const ushort* __restrict__ Xin,
                                                 void* __restrict__ Out,
                                                 float* __restrict__ Out2,
                                                 const float* __restrict__ mask,
                                                 int O, int K) {
    const int blk = blockIdx.x;
    const int b = blk >> 2;
    const int t0 = (blk & 3) * 128;
    const int o0 = blockIdx.y * TN;
    const int kz = (KSPLIT > 1) ? blockIdx.z : 0;
    const int tid = threadIdx.x;
    const int wid = tid >> 6, lane = tid & 63, ln = lane & 15, q = lane >> 4;
    constexpr int MF = (TN == 128) ? 4 : 2;
    constexpr int TSH = (TN == 128) ? 7 : 6;
    const int msub = (TN == 128) ? (wid & 1) * 64 : wid * 32;
    const int nsub = (TN == 128) ? (wid >> 1) * 64 : 0;

    __shared__ ushort Xs[130][40];      // rows t0-1 .. t0+128 (col-swizzled)
    __shared__ ushort Ws[3 * TN][40];   // [tap*TN + o][c]     (col-swizzled)

    f32x4 acc[MF][4] = {};

    const int Kc = K / KSPLIT;
    const int cbase = kz * Kc;
    const int NC = Kc >> 5;

    const int rx = tid >> 1;            // X main row 0..127
    const int cx = (tid & 1) << 4;
    const int rw0 = tid >> 2;           // W row stepper
    const int cw = (tid & 3) << 3;

    const ushort* Xb = Xin + (size_t)b * TT * K;

    for (int cc = 0; cc < NC; ++cc) {
        const int c0 = cbase + (cc << 5);
        __syncthreads();
        {   // X main rows (always in range: t0+rx in [0,TT))
            const ushort* xp = Xb + (size_t)(t0 + rx) * K + c0 + cx;
            *(uint4*)&Xs[rx + 1][swz(rx + 1, cx)] = *(const uint4*)xp;
            *(uint4*)&Xs[rx + 1][swz(rx + 1, cx + 8)] = *(const uint4*)(xp + 8);
        }
        if (tid < 8) {   // halo rows t0-1 and t0+128 (zero out of range)
            const int pr = (tid < 4) ? 0 : 129;
            const int cu = (tid & 3) << 3;
            const int tg = t0 + ((tid < 4) ? -1 : 128);
            uint4 v = make_uint4(0u, 0u, 0u, 0u);
            if (tg >= 0 && tg < TT)
                v = *(const uint4*)(Xb + (size_t)tg * K + c0 + cu);
            *(uint4*)&Xs[pr][swz(pr, cu)] = v;
        }
        #pragma unroll
        for (int j = 0; j < 3 * TN / 64; ++j) {   // W: 3*TN rows
            const int r = rw0 + j * 64;
            const int tap = r >> TSH, o = r & (TN - 1);
            const ushort* wp = Wt + ((size_t)(tap * O + o0 + o)) * K + c0 + cw;
            *(uint4*)&Ws[r][swz(r, cw)] = *(const uint4*)wp;
        }
        __syncthreads();
        #pragma unroll
        for (int tap = 0; tap < 3; ++tap) {
            short8 afr[MF], bfr[4];
            #pragma unroll
            for (int mi = 0; mi < MF; ++mi) {
                const int xr = msub + mi * 16 + ln + tap;
                afr[mi] = *(const short8*)&Xs[xr][swz(xr, q * 8)];
            }
            #pragma unroll
            for (int ni = 0; ni < 4; ++ni) {
                const int wr = tap * TN + nsub + ni * 16 + ln;
                bfr[ni] = *(const short8*)&Ws[wr][swz(wr, q * 8)];
            }
            #pragma unroll
            for (int mi = 0; mi < MF; ++mi)
                #pragma unroll
                for (int ni = 0; ni < 4; ++ni)
                    acc[mi][ni] = __builtin_amdgcn_mfma_f32_16x16x32_bf16(
                        afr[mi], bfr[ni], acc[mi][ni], 0, 0, 0);
        }
    }

    #pragma unroll
    for (int ni = 0; ni < 4; ++ni) {
        const int o = o0 + nsub + ni * 16 + ln;
        #pragma unroll
        for (int mi = 0; mi < MF; ++mi) {
            const int t = t0 + msub + mi * 16 + q * 4;
            if (MODE == 1) {
                const float bv = bias[o];
                ushort* Op = (ushort*)Out;
                #pragma unroll
                for (int r = 0; r < 4; ++r) {
                    float v = fmaxf(acc[mi][ni][r] + bv, 0.f) * mask[b * TT + t + r];
                    Op[((size_t)(b * TT) + t + r) * (size_t)O + o] = f2bs(v);
                }
            } else {
                float* Op = (kz < 2) ? ((float*)Out + (size_t)kz * BCTS)
                                     : (Out2 + (size_t)(kz - 2) * BCTS);
                #pragma unroll
                for (int r = 0; r < 4; ++r)
                    Op[((size_t)(b * TT) + t + r) * O + o] = acc[mi][ni][r];
            }
        }
    }
}

// ---------------------------------------------------------------------------
// Fused relative-position attention: one independent wave per 16 q-rows.
// (unchanged from round 11)
__global__ __launch_bounds__(256) void fattn_kernel(const ushort* __restrict__ qkvt,
                                                    const float* __restrict__ mask,
                                                    const float* __restrict__ erk,
                                                    const float* __restrict__ erv,
                                                    ushort* __restrict__ xto) {
    const int tid = threadIdx.x;
    const int wm = tid >> 6;
    const int lane = tid & 63;
    const int ln = lane & 15;
    const int q4 = lane >> 4;
    const int bh = blockIdx.y;
    const int b = bh >> 3, h = bh & 7;
    const int t0g = blockIdx.x * 64 + wm * 16;

    __shared__ float ervs[2 * WW + 1][DKK];
    __shared__ float msS[TT];
    __shared__ float relS[4][16][22];
    __shared__ float band[4][16][24];
    __shared__ ushort Pt[4][16][40];

    for (int i = tid; i < (2 * WW + 1) * DKK; i += 256)
        ervs[i / DKK][i % DKK] = erv[i];
    for (int i = tid; i < TT; i += 256)
        msS[i] = mask[b * TT + i];

    #pragma unroll
    for (int i = 0; i < 6; ++i) {
        const int idx = lane + i * 64;
        ((float*)band[wm])[idx] = -1e30f;
    }

    const ushort* qrow = qkvt + ((size_t)(b * TT + t0g + ln) * CC + h * DKK);
    const short8 qb0 = *(const short8*)(qrow + q4 * 8);
    const short8 qb1 = *(const short8*)(qrow + 32 + q4 * 8);

    {
        const float* ekL = erk;
        short8 ea0, ea1;
        {
            const float* ep = ekL + ln * DKK + q4 * 8;
            #pragma unroll
            for (int j = 0; j < 8; ++j) ea0[j] = (short)f2bs(ep[j]);
            #pragma unroll
            for (int j = 0; j < 8; ++j) ea1[j] = (short)f2bs(ep[32 + j]);
        }
        f32x4 c0 = {};
        c0 = __builtin_amdgcn_mfma_f32_16x16x32_bf16(ea0, qb0, c0, 0, 0, 0);
        c0 = __builtin_amdgcn_mfma_f32_16x16x32_bf16(ea1, qb1, c0, 0, 0, 0);
        #pragma unroll
        for (int r = 0; r < 4; ++r)
            relS[wm][ln][q4 * 4 + r] = c0[r] * 0.125f;
        short8 eb0 = {}, eb1 = {};
        if (ln < 2 * WW + 1 - 16) {
            const float* ep = ekL + (16 + ln) * DKK + q4 * 8;
            #pragma unroll
            for (int j = 0; j < 8; ++j) eb0[j] = (short)f2bs(ep[j]);
            #pragma unroll
            for (int j = 0; j < 8; ++j) eb1[j] = (short)f2bs(ep[32 + j]);
        }
        f32x4 c1 = {};
        c1 = __builtin_amdgcn_mfma_f32_16x16x32_bf16(eb0, qb0, c1, 0, 0, 0);
        c1 = __builtin_amdgcn_mfma_f32_16x16x32_bf16(eb1, qb1, c1, 0, 0, 0);
        #pragma unroll
        for (int r = 0; r < 4; ++r) {
            const int w = 16 + q4 * 4 + r;
            if (w < 2 * WW + 1) relS[wm][ln][w] = c1[r] * 0.125f;
        }
    }

    __syncthreads();

    const float mt = msS[t0g + ln];

    float m_run = -1e30f, l_run = 0.f;
    f32x4 Oacc[4] = {};

    const ushort* Kbase = qkvt + BCTS + ((size_t)(b * TT) * CC + h * DKK);
    const ushort* Vbase = qkvt + 2 * BCTS + ((size_t)(b * CC + h * DKK) * TT);

    for (int s0 = 0; s0 < TT; s0 += 32) {
        const ushort* klo = Kbase + (size_t)(s0 + ln) * CC;
        const ushort* khi = klo + 16 * CC;
        const short8 ka0 = *(const short8*)(klo + q4 * 8);
        const short8 ka1 = *(const short8*)(klo + 32 + q4 * 8);
        const short8 kb0 = *(const short8*)(khi + q4 * 8);
        const short8 kb1 = *(const short8*)(khi + 32 + q4 * 8);

        f32x4 slo = {}, shi = {};
        slo = __builtin_amdgcn_mfma_f32_16x16x32_bf16(ka0, qb0, slo, 0, 0, 0);
        slo = __builtin_amdgcn_mfma_f32_16x16x32_bf16(ka1, qb1, slo, 0, 0, 0);
        shi = __builtin_amdgcn_mfma_f32_16x16x32_bf16(kb0, qb0, shi, 0, 0, 0);
        shi = __builtin_amdgcn_mfma_f32_16x16x32_bf16(kb1, qb1, shi, 0, 0, 0);

        float v[2][4];
        float bmax = -1e30f;
        const int tg = t0g + ln;
        #pragma unroll
        for (int half = 0; half < 2; ++half) {
            #pragma unroll
            for (int r = 0; r < 4; ++r) {
                const int s = s0 + half * 16 + q4 * 4 + r;
                const int wb = s - tg + WW;
                float vv = (half ? shi[r] : slo[r]) * 0.125f;
                if ((unsigned)wb <= 2u * WW) vv += relS[wm][ln][wb];
                if (mt * msS[s] == 0.f) vv = -1e4f;
                if ((unsigned)wb <= 2u * WW) band[wm][ln][wb] = vv;
                v[half][r] = vv;
                bmax = fmaxf(bmax, vv);
            }
        }
        bmax = fmaxf(bmax, __shfl_xor(bmax, 16, 64));
        bmax = fmaxf(bmax, __shfl_xor(bmax, 32, 64));

        const float mnew = fmaxf(m_run, bmax);
        const float alpha = __expf(m_run - mnew);
        m_run = mnew;

        float rsum = 0.f;
        ushort pb[8];
        #pragma unroll
        for (int half = 0; half < 2; ++half)
            #pragma unroll
            for (int r = 0; r < 4; ++r) {
                const float p = __expf(v[half][r] - mnew);
                rsum += p;
                pb[half * 4 + r] = f2bs(p);
            }
        rsum += __shfl_xor(rsum, 16, 64);
        rsum += __shfl_xor(rsum, 32, 64);
        l_run = l_run * alpha + rsum;

        *(uint2*)&Pt[wm][ln][q4 * 4] = *(const uint2*)&pb[0];
        *(uint2*)&Pt[wm][ln][16 + q4 * 4] = *(const uint2*)&pb[4];

        #pragma unroll
        for (int r = 0; r < 4; ++r) {
            const float alr = __shfl(alpha, q4 * 4 + r, 64);
            #pragma unroll
            for (int dt = 0; dt < 4; ++dt) Oacc[dt][r] *= alr;
        }

        const short8 pa = *(const short8*)&Pt[wm][ln][q4 * 8];
        #pragma unroll
        for (int dt = 0; dt < 4; ++dt) {
            const short8 vb = *(const short8*)(Vbase + (size_t)(dt * 16 + ln) * TT + s0 + q4 * 8);
            Oacc[dt] = __builtin_amdgcn_mfma_f32_16x16x32_bf16(pa, vb, Oacc[dt], 0, 0, 0);
        }
    }

    float mr[4], invl[4];
    #pragma unroll
    for (int r = 0; r < 4; ++r) {
        mr[r] = __shfl(m_run, q4 * 4 + r, 64);
        invl[r] = 1.f / __shfl(l_run, q4 * 4 + r, 64);
    }
    f32x4 racc[4] = {};
    for (int w = 0; w <= 2 * WW; ++w) {
        float ev[4];
        #pragma unroll
        for (int dt = 0; dt < 4; ++dt) ev[dt] = ervs[w][dt * 16 + ln];
        #pragma unroll
        for (int r = 0; r < 4; ++r) {
            const float pw = __expf(band[wm][q4 * 4 + r][w] - mr[r]);
            #pragma unroll
            for (int dt = 0; dt < 4; ++dt) racc[dt][r] += pw * ev[dt];
        }
    }
    #pragma unroll
    for (int r = 0; r < 4; ++r) {
        const int t = t0g + q4 * 4 + r;
        #pragma unroll
        for (int dt = 0; dt < 4; ++dt)
            xto[((size_t)(b * TT) + t) * CC + h * DKK + dt * 16 + ln] =
                f2bs((Oacc[dt][r] + racc[dt][r]) * invl[r]);
    }
}

// ---------------------------------------------------------------------------
// x = LN(x + y*(maskY?m:1)), y = sum(p0..p3 present) (+ biasc[c]);
// emits Xt bf16 [B,T,C]. All tensors [B,T,C]. One wave per (b,t) row.
__global__ __launch_bounds__(256) void addln_kernel(float* __restrict__ x,
                                                    const float* __restrict__ p0,
                                                    const float* __restrict__ p1,
                                                    const float* __restrict__ p2,
                                                    const float* __restrict__ p3,
                                                    const float* __restrict__ biasc,
                                                    const float* __restrict__ g,
                                                    const float* __restrict__ bt,
                                                    const float* __restrict__ mask,
                                                    int maskY,
                                                    ushort* __restrict__ xtout,
                                                    int maskOut) {
    const int row = blockIdx.x * 4 + (threadIdx.x >> 6);   // b*TT + t
    const int lane = threadIdx.x & 63;
    const float m = mask[row];
    const float mv = maskY ? m : 1.f;
    const float mo = maskOut ? m : 1.f;
    const size_t base = (size_t)row * CC;
    const int c0 = lane * 8;

    f32x4 y0 = *(const f32x4*)(p0 + base + c0);
    f32x4 y1 = *(const f32x4*)(p0 + base + c0 + 4);
    if (p1) {
        y0 += *(const f32x4*)(p1 + base + c0);
        y1 += *(const f32x4*)(p1 + base + c0 + 4);
    }
    if (p2) {
        y0 += *(const f32x4*)(p2 + base + c0);
        y1 += *(const f32x4*)(p2 + base + c0 + 4);
    }
    if (p3) {
        y0 += *(const f32x4*)(p3 + base + c0);
        y1 += *(const f32x4*)(p3 + base + c0 + 4);
    }
    if (biasc) {
        y0 += *(const f32x4*)(biasc + c0);
        y1 += *(const f32x4*)(biasc + c0 + 4);
    }

    f32x4 a0 = *(const f32x4*)(x + base + c0);
    f32x4 a1 = *(const f32x4*)(x + base + c0 + 4);
    f32x4 v0, v1;
    #pragma unroll
    for (int r = 0; r < 4; ++r) {
        v0[r] = a0[r] + y0[r] * mv;
        v1[r] = a1[r] + y1[r] * mv;
    }

    float s = 0.f, s2 = 0.f;
    #pragma unroll
    for (int r = 0; r < 4; ++r) {
        s += v0[r] + v1[r];
        s2 += v0[r] * v0[r] + v1[r] * v1[r];
    }
    s = wave_sum(s);
    s2 = wave_sum(s2);
    const float mean = s * (1.f / CC);
    const float var = s2 * (1.f / CC) - mean * mean;
    const float rstd = rsqrtf(var + 1e-5f);

    f32x4 g0 = *(const f32x4*)(g + c0);
    f32x4 g1v = *(const f32x4*)(g + c0 + 4);
    f32x4 bt0 = *(const f32x4*)(bt + c0);
    f32x4 bt1 = *(const f32x4*)(bt + c0 + 4);
    f32x4 o0, o1;
    ushort ob[8];
    #pragma unroll
    for (int r = 0; r < 4; ++r) {
        o0[r] = (v0[r] - mean) * rstd * g0[r] + bt0[r];
        o1[r] = (v1[r] - mean) * rstd * g1v[r] + bt1[r];
        ob[r] = f2bs(o0[r] * mo);
        ob[4 + r] = f2bs(o1[r] * mo);
    }
    *(f32x4*)(x + base + c0) = o0;
    *(f32x4*)(x + base + c0 + 4) = o1;
    *(uint4*)(xtout + base + c0) = *(const uint4*)ob;
}

// ---------------------------------------------------------------------------
extern "C" void kernel_launch(void* const* d_in, const int* in_sizes, int n_in,
                              void* d_out, int out_size, void* d_ws, size_t ws_size,
                              hipStream_t stream) {
    const float* x_in = (const float*)d_in[0];
    const float* mask = (const float*)d_in[1];
    const float* Wq = (const float*)d_in[2];
    const float* bq = (const float*)d_in[3];
    const float* Wk = (const float*)d_in[4];
    const float* bk = (const float*)d_in[5];
    const float* Wv = (const float*)d_in[6];
    const float* bv = (const float*)d_in[7];
    const float* Wo = (const float*)d_in[8];
    const float* bo = (const float*)d_in[9];
    const float* erk = (const float*)d_in[10];
    const float* erv = (const float*)d_in[11];
    const float* g1 = (const float*)d_in[12];
    const float* b1 = (const float*)d_in[13];
    const float* g2 = (const float*)d_in[14];
    const float* b2 = (const float*)d_in[15];
    const float* W1 = (const float*)d_in[16];
    const float* bf1 = (const float*)d_in[17];
    const float* W2 = (const float*)d_in[18];
    const float* bf2 = (const float*)d_in[19];

    float* xf = (float*)d_ws;                    // fp32 [B,T,C]
    ushort* Xt = (ushort*)(xf + BCTS);           // bf16 [B,T,C]
    ushort* qkvt = Xt + BCTS;
    ushort* Xto = qkvt + 3 * BCTS;
    float* parts = (float*)(Xto + BCTS);         // fp32 [B,T,C] p0 | p1
    ushort* Midt = (ushort*)(parts + 2 * BCTS);  // [B,T,F] bf16
    ushort* Wqkv = Midt + 4 * BCTS;
    float* bqkv = (float*)(Wqkv + (size_t)1536 * 512);
    ushort* Wot = (ushort*)(bqkv + 1536);
    ushort* W1t = Wot + (size_t)CC * CC;
    ushort* W2t = W1t + (size_t)3 * FF * CC;

    // conv2 partials p2,p3 reuse the qkvt region (dead during the FFN phase;
    // p3 also covers Xto, which is dead after the O-projection reads it).
    float* P23 = (float*)qkvt;

    init_trans<<<dim3(TT / 32, CC / 32, BB), 256, 0, stream>>>(x_in, mask, xf, Xt);

    const size_t nW = 786432 + 262144 + 3145728 + 3145728;
    const int wcvtBlocks = (int)((nW + 255) / 256);

    for (int L = 0; L < NLAYERS; ++L) {
        wcvt_layer<<<wcvtBlocks, 256, 0, stream>>>(
            Wq + (size_t)L * CC * CC, Wk + (size_t)L * CC * CC, Wv + (size_t)L * CC * CC,
            bq + (size_t)L * CC, bk + (size_t)L * CC, bv + (size_t)L * CC,
            Wo + (size_t)L * CC * CC,
            W1 + (size_t)L * 3 * FF * CC, W2 + (size_t)L * 3 * FF * CC,
            Wqkv, bqkv, Wot, W1t, W2t);

        // fused QKV (N=1536)
        gemm128<2, 128><<<dim3(32, 12), 256, 0, stream>>>(
            Wqkv, bqkv, Xt, qkvt, mask, 1536, CC, 1, 4, 1);

        // fused attention (barrier-free waves, writes Xto directly)
        fattn_kernel<<<dim3(TT / 64, BB * HH), 256, 0, stream>>>(
            qkvt, mask, erk + (size_t)L * (2 * WW + 1) * DKK,
            erv + (size_t)L * (2 * WW + 1) * DKK, Xto);

        // O-projection (K-split x2, raw partials) + residual LN (bias in LN)
        gemm128<0, 64><<<dim3(32, 8, 2), 256, 0, stream>>>(
            Wot, nullptr, Xto, parts, mask, CC, CC, 1, 4, 2);
        addln_kernel<<<BB * TT / 4, 256, 0, stream>>>(
            xf, parts, parts + BCTS, nullptr, nullptr, bo + (size_t)L * CC,
            g1 + (size_t)L * CC, b1 + (size_t)L * CC, mask, 0, Xt, 1);

        // FFN: conv1 (TN=128) -> conv2 (TN=64, K-split x4) -> LN
        conv_gemm<128, 1, 1><<<dim3(32, FF / 128, 1), 256, 0, stream>>>(
            W1t, bf1 + (size_t)L * FF, Xt, Midt, nullptr, mask, FF, CC);
        conv_gemm<64, 4, 3><<<dim3(32, CC / 64, 4), 256, 0, stream>>>(
            W2t, nullptr, Midt, parts, P23, mask, CC, FF);
        addln_kernel<<<BB * TT / 4, 256, 0, stream>>>(
            xf, parts, parts + BCTS, P23, P23 + BCTS, bf2 + (size_t)L * CC,
            g2 + (size_t)L * CC, b2 + (size_t)L * CC, mask, 1, Xt, 0);
    }

    final_kernel<<<dim3(TT / 32, CC / 32, BB), 256, 0, stream>>>(xf, mask, (float*)d_out);
}